// Round 4
// baseline (564.664 us; speedup 1.0000x reference)
//
#include <hip/hip_runtime.h>

// FlashQwenAttention: x@wq/wk/wv -> rmsnorm(q,k) -> rope -> GQA causal attn -> ctx@wo
// B=2 S=1024 H=4096 NH=32 NKV=8 HD=128. Inputs fp32; internal bf16 MFMA.
// R4: flash_attn v2 — 128-row Q tiles, double-buffered K/V global_load_lds
// with prefetch-after-barrier (DMA overlaps compute), masked-tile skip;
// wq/wk/wv transposes merged into one launch.

#define NH_ 32
#define NKV_ 8
#define HD_ 128
#define SEQ_ 1024
#define HID_ 4096
#define NQKV_ 6144

typedef unsigned short u16;
typedef __bf16 bf16x8 __attribute__((ext_vector_type(8)));
typedef float f32x4 __attribute__((ext_vector_type(4)));

__device__ __forceinline__ u16 f2bf(float f) {
  unsigned int u = __float_as_uint(f);
  return (u16)((u + 0x7FFFu + ((u >> 16) & 1u)) >> 16);
}
__device__ __forceinline__ float bf2f(u16 u) {
  return __uint_as_float(((unsigned int)u) << 16);
}
__device__ __forceinline__ f32x4 mfma16(bf16x8 a, bf16x8 b, f32x4 c) {
  return __builtin_amdgcn_mfma_f32_16x16x32_bf16(a, b, c, 0, 0, 0);
}
__device__ __forceinline__ void gld16(u16* lds, const u16* g) {
  __builtin_amdgcn_global_load_lds(
      (const __attribute__((address_space(1))) unsigned int*)g,
      (__attribute__((address_space(3))) unsigned int*)lds, 16, 0, 0);
}

// ---------------- prep: fp32 -> bf16 elementwise (X) ----------------
__global__ __launch_bounds__(256) void cvt_bf16(const float* __restrict__ src,
                                                u16* __restrict__ dst) {
  int i = (blockIdx.x * 256 + threadIdx.x) * 8;
  float4 a = *(const float4*)(src + i);
  float4 b = *(const float4*)(src + i + 4);
  u16 o[8];
  o[0] = f2bf(a.x); o[1] = f2bf(a.y); o[2] = f2bf(a.z); o[3] = f2bf(a.w);
  o[4] = f2bf(b.x); o[5] = f2bf(b.y); o[6] = f2bf(b.z); o[7] = f2bf(b.w);
  *(uint4*)(dst + i) = *(uint4*)&o[0];
}

// ---------------- prep: transpose + convert one weight ----------------
__global__ __launch_bounds__(256) void transpose_cvt(
    const float* __restrict__ src, int ldn, u16* __restrict__ dst, int K) {
  __shared__ float t[32][33];
  const int k0 = blockIdx.x * 32, n0 = blockIdx.y * 32;
  const int c = threadIdx.x & 31, r4 = threadIdx.x >> 5;
#pragma unroll
  for (int i = 0; i < 4; ++i) {
    int r = r4 + i * 8;
    t[r][c] = src[(size_t)(k0 + r) * ldn + n0 + c];
  }
  __syncthreads();
#pragma unroll
  for (int i = 0; i < 4; ++i) {
    int r = r4 + i * 8;
    dst[(size_t)(n0 + r) * K + k0 + c] = f2bf(t[c][r]);
  }
}

// ---------------- prep: wq|wk|wv transpose in one launch ----------------
__global__ __launch_bounds__(256) void transpose_cvt3(
    const float* __restrict__ wq, const float* __restrict__ wk,
    const float* __restrict__ wv, u16* __restrict__ dst) {
  __shared__ float t[32][33];
  const int k0 = blockIdx.x * 32;
  const int y = blockIdx.y;
  const float* src;
  int ldn, n0;
  size_t dofs;
  if (y < 128) { src = wq; ldn = 4096; n0 = y * 32; dofs = 0; }
  else if (y < 160) { src = wk; ldn = 1024; n0 = (y - 128) * 32; dofs = (size_t)4096 * 4096; }
  else { src = wv; ldn = 1024; n0 = (y - 160) * 32; dofs = (size_t)5120 * 4096; }
  const int c = threadIdx.x & 31, r4 = threadIdx.x >> 5;
#pragma unroll
  for (int i = 0; i < 4; ++i) {
    int r = r4 + i * 8;
    t[r][c] = src[(size_t)(k0 + r) * ldn + n0 + c];
  }
  __syncthreads();
#pragma unroll
  for (int i = 0; i < 4; ++i) {
    int r = r4 + i * 8;
    dst[dofs + (size_t)(n0 + r) * HID_ + k0 + c] = f2bf(t[c][r]);
  }
}

// ---------------- prep: V section of qkv -> VT [b][kvh][d][s] bf16 -------
__global__ __launch_bounds__(256) void v_transpose(const u16* __restrict__ QKV,
                                                   u16* __restrict__ VT) {
  __shared__ u16 t[32][33];
  const int s0 = blockIdx.x * 32, d0 = blockIdx.y * 32;
  const int bkvh = blockIdx.z;
  const int b = bkvh >> 3, kvh = bkvh & 7;
  const int c = threadIdx.x & 31, r8 = threadIdx.x >> 5;
#pragma unroll
  for (int i = 0; i < 4; ++i) {
    int r = r8 + i * 8;
    t[r][c] = QKV[(size_t)(b * SEQ_ + s0 + r) * NQKV_ + 5120 + kvh * 128 + d0 + c];
  }
  __syncthreads();
#pragma unroll
  for (int i = 0; i < 4; ++i) {
    int r = r8 + i * 8;
    VT[(size_t)(bkvh * HD_ + d0 + r) * SEQ_ + s0 + c] = t[c][r];
  }
}

// ---------------- m97-style GEMM: C[M x N] = A[M x K] @ Bt[N x K]^T --------
template <bool F32OUT>
__global__ __launch_bounds__(256) void gemm_bt(const u16* __restrict__ A,
                                               const u16* __restrict__ Bt,
                                               void* __restrict__ Cv, int K,
                                               int ldc) {
  __shared__ u16 As[128 * 32];
  __shared__ u16 Bs[128 * 32];
  const int bn = blockIdx.x, bm = blockIdx.y;
  const int tid = threadIdx.x, lane = tid & 63, w = tid >> 6;
  const int wr = w >> 1, wc = w & 1, ln = lane & 15, quad = lane >> 4;

  const int srow = w * 32 + (lane >> 2);
  const int skk = (lane & 3) * 8;
  const u16* ag = A + (size_t)(bm * 128 + srow) * K + skk;
  const u16* bg = Bt + (size_t)(bn * 128 + srow) * K + skk;
  u16* asd = &As[w * 1024];
  u16* bsd = &Bs[w * 1024];

  f32x4 acc[4][4];
#pragma unroll
  for (int i = 0; i < 4; ++i)
#pragma unroll
    for (int j = 0; j < 4; ++j)
#pragma unroll
      for (int r = 0; r < 4; ++r) acc[i][j][r] = 0.0f;

  for (int kb = 0; kb < K / 32; ++kb) {
    gld16(asd, ag);
    gld16(asd + 512, ag + 16 * (size_t)K);
    gld16(bsd, bg);
    gld16(bsd + 512, bg + 16 * (size_t)K);
    ag += 32;
    bg += 32;
    __syncthreads();
    bf16x8 af[4], bfr[4];
#pragma unroll
    for (int i = 0; i < 4; ++i)
      af[i] = *(const bf16x8*)&As[(wr * 64 + i * 16 + ln) * 32 + quad * 8];
#pragma unroll
    for (int j = 0; j < 4; ++j)
      bfr[j] = *(const bf16x8*)&Bs[(wc * 64 + j * 16 + ln) * 32 + quad * 8];
#pragma unroll
    for (int i = 0; i < 4; ++i)
#pragma unroll
      for (int j = 0; j < 4; ++j) acc[i][j] = mfma16(af[i], bfr[j], acc[i][j]);
    __syncthreads();
  }
#pragma unroll
  for (int i = 0; i < 4; ++i) {
#pragma unroll
    for (int r = 0; r < 4; ++r) {
      int grow = bm * 128 + wr * 64 + i * 16 + quad * 4 + r;
      int gcol = bn * 128 + wc * 64 + ln;
      if (F32OUT) {
        float* dst = (float*)Cv + (size_t)grow * ldc + gcol;
#pragma unroll
        for (int j = 0; j < 4; ++j) dst[j * 16] = acc[i][j][r];
      } else {
        u16* dst = (u16*)Cv + (size_t)grow * ldc + gcol;
#pragma unroll
        for (int j = 0; j < 4; ++j) dst[j * 16] = f2bf(acc[i][j][r]);
      }
    }
  }
}

// ---------------- RMSNorm + RoPE (q prescaled by scale*log2e) -------------
__global__ __launch_bounds__(256) void norm_rope(
    const u16* __restrict__ QKV, const float* __restrict__ QW,
    const float* __restrict__ KW, u16* __restrict__ QB, u16* __restrict__ KB) {
  const float QSCALE = 0.08838834764831845f * 1.4426950408889634f;
  int vec = blockIdx.x * 4 + (threadIdx.x >> 6);
  int lane = threadIdx.x & 63;
  const u16* src;
  u16* dst;
  const float* nw;
  int m;
  float outsc;
  if (vec < 65536) {  // q
    m = vec >> 5;
    int hh = vec & 31;
    src = QKV + (size_t)m * NQKV_ + hh * 128;
    int b = m >> 10, s = m & 1023;
    dst = QB + (size_t)((b * NH_ + hh) * SEQ_ + s) * HD_;
    nw = QW;
    outsc = QSCALE;
  } else {  // k
    int vk = vec - 65536;
    m = vk >> 3;
    int kvh = vk & 7;
    src = QKV + (size_t)m * NQKV_ + 4096 + kvh * 128;
    int b = m >> 10, s = m & 1023;
    dst = KB + (size_t)((b * NKV_ + kvh) * SEQ_ + s) * HD_;
    nw = KW;
    outsc = 1.0f;
  }
  float t1 = bf2f(src[lane]), t2 = bf2f(src[lane + 64]);
  float ss = t1 * t1 + t2 * t2;
#pragma unroll
  for (int off = 32; off >= 1; off >>= 1) ss += __shfl_xor(ss, off);
  float scale = rsqrtf(ss * (1.0f / 128.0f) + 1e-6f) * outsc;
  float n1 = t1 * scale * nw[lane];
  float n2 = t2 * scale * nw[lane + 64];
  int spos = m & 1023;
  float invf = powf(10000.0f, -(float)lane * (1.0f / 64.0f));
  float ang = (float)spos * invf;
  float sn, cs;
  sincosf(ang, &sn, &cs);
  dst[lane] = f2bf(n1 * cs - n2 * sn);
  dst[lane + 64] = f2bf(n1 * sn + n2 * cs);
}

// ---------------- GQA causal flash attention v2 ----------------
// block = (b, h, 128-row q tile); 4 waves x 32 q rows (2 x 16-row tiles);
// 64-key tiles, double-buffered DMA staging, qt-descending dispatch.
__global__ __launch_bounds__(256, 2) void flash_attn(
    const u16* __restrict__ QB, const u16* __restrict__ KB,
    const u16* __restrict__ VT, u16* __restrict__ CTX) {
  __shared__ u16 Ks[2][4][64][32];   // [buf][kc][key][k-seg]  32 KB
  __shared__ u16 Vs[2][2][128][32];  // [buf][kchunk][d][key]  32 KB
  __shared__ u16 Pl[4][16][72];      // per-wave P, A-layout, swizzled

  const int bid = blockIdx.x;
  const int qt = 7 - (bid >> 6);  // long blocks first
  const int h = bid & 31, b = (bid >> 5) & 1;
  const int kvh = h >> 2;
  const int tid = threadIdx.x, w = tid >> 6, lane = tid & 63;
  const int ln = lane & 15, quad = lane >> 4;

  const u16* qbase = QB + (size_t)((b * NH_ + h) * SEQ_ + qt * 128) * HD_;
  bf16x8 qf[2][4];
#pragma unroll
  for (int rt = 0; rt < 2; ++rt)
#pragma unroll
    for (int kc = 0; kc < 4; ++kc)
      qf[rt][kc] = *(const bf16x8*)(qbase +
                                    (size_t)(w * 32 + rt * 16 + ln) * HD_ +
                                    kc * 32 + quad * 8);

  f32x4 o[2][8];
#pragma unroll
  for (int rt = 0; rt < 2; ++rt)
#pragma unroll
    for (int t = 0; t < 8; ++t)
#pragma unroll
      for (int r = 0; r < 4; ++r) o[rt][t][r] = 0.0f;
  float m_r[2][4] = {{-3e38f, -3e38f, -3e38f, -3e38f},
                     {-3e38f, -3e38f, -3e38f, -3e38f}};
  float l_r[2][4] = {{0, 0, 0, 0}, {0, 0, 0, 0}};

  const u16* krow = KB + (size_t)((b * NKV_ + kvh) * SEQ_ + w * 16 + (lane >> 2)) * HD_ +
                    (lane & 3) * 8;
  const u16* vrow = VT + (size_t)((b * NKV_ + kvh) * HD_ + w * 32 + (lane >> 2)) * SEQ_ +
                    (lane & 3) * 8;
  const int pswz = ((ln >> 3) & 1) << 3;
  const int nkt = 2 * qt + 2;
  const int wave_max_row = qt * 128 + w * 32 + 31;

  // stage tile 0 into buf 0
#pragma unroll
  for (int i = 0; i < 4; ++i) gld16(&Ks[0][i][w * 16][0], krow + i * 32);
#pragma unroll
  for (int i = 0; i < 4; ++i)
    gld16(&Vs[0][i & 1][w * 32 + (i >> 1) * 16][0],
          vrow + (size_t)(i >> 1) * 16 * SEQ_ + (i & 1) * 32);

  for (int kt = 0; kt < nkt; ++kt) {
    const int key0 = kt * 64;
    const int buf = kt & 1;
    __syncthreads();  // drains own DMA (vmcnt 0) then barrier

    if (kt + 1 < nkt) {  // prefetch next tile; overlaps compute below
      const int nk0 = key0 + 64, nbuf = buf ^ 1;
#pragma unroll
      for (int i = 0; i < 4; ++i)
        gld16(&Ks[nbuf][i][w * 16][0], krow + (size_t)nk0 * HD_ + i * 32);
#pragma unroll
      for (int i = 0; i < 4; ++i)
        gld16(&Vs[nbuf][i & 1][w * 32 + (i >> 1) * 16][0],
              vrow + (size_t)(i >> 1) * 16 * SEQ_ + nk0 + (i & 1) * 32);
    }

    if (key0 > wave_max_row) continue;  // fully-masked tile for this wave
    const bool diag = (kt >= 2 * qt);

#pragma unroll
    for (int rt = 0; rt < 2; ++rt) {
      f32x4 sc[4];
#pragma unroll
      for (int t2 = 0; t2 < 4; ++t2) {
#pragma unroll
        for (int r = 0; r < 4; ++r) sc[t2][r] = 0.0f;
#pragma unroll
        for (int kc = 0; kc < 4; ++kc) {
          bf16x8 kf = *(const bf16x8*)&Ks[buf][kc][t2 * 16 + ln][quad * 8];
          sc[t2] = mfma16(qf[rt][kc], kf, sc[t2]);
        }
      }

      float p[4][4], alpha[4];
#pragma unroll
      for (int r = 0; r < 4; ++r) {
        float s0 = sc[0][r], s1 = sc[1][r], s2 = sc[2][r], s3 = sc[3][r];
        if (diag) {
          const int qi = qt * 128 + w * 32 + rt * 16 + quad * 4 + r;
          if (key0 + ln > qi) s0 = -3e38f;
          if (key0 + 16 + ln > qi) s1 = -3e38f;
          if (key0 + 32 + ln > qi) s2 = -3e38f;
          if (key0 + 48 + ln > qi) s3 = -3e38f;
        }
        float mx = fmaxf(fmaxf(s0, s1), fmaxf(s2, s3));
#pragma unroll
        for (int off = 1; off < 16; off <<= 1)
          mx = fmaxf(mx, __shfl_xor(mx, off));
        float mnew = fmaxf(m_r[rt][r], mx);
        alpha[r] = exp2f(m_r[rt][r] - mnew);
        p[0][r] = exp2f(s0 - mnew);
        p[1][r] = exp2f(s1 - mnew);
        p[2][r] = exp2f(s2 - mnew);
        p[3][r] = exp2f(s3 - mnew);
        float rs = p[0][r] + p[1][r] + p[2][r] + p[3][r];
#pragma unroll
        for (int off = 1; off < 16; off <<= 1) rs += __shfl_xor(rs, off);
        l_r[rt][r] = l_r[rt][r] * alpha[r] + rs;
        m_r[rt][r] = mnew;
      }
#pragma unroll
      for (int t = 0; t < 8; ++t)
#pragma unroll
        for (int r = 0; r < 4; ++r) o[rt][t][r] *= alpha[r];

      // P: C-layout -> A-layout via per-wave LDS (in-order within wave)
#pragma unroll
      for (int r = 0; r < 4; ++r) {
        const int row = quad * 4 + r;
        const int wswz = ((row >> 3) & 1) << 3;
#pragma unroll
        for (int t2 = 0; t2 < 4; ++t2)
          Pl[w][row][(t2 * 16 + ln) ^ wswz] = f2bf(p[t2][r]);
      }
      bf16x8 af0 = *(const bf16x8*)&Pl[w][ln][(quad * 8) ^ pswz];
      bf16x8 af1 = *(const bf16x8*)&Pl[w][ln][32 + ((quad * 8) ^ pswz)];
#pragma unroll
      for (int t = 0; t < 8; ++t) {
        bf16x8 vf0 = *(const bf16x8*)&Vs[buf][0][t * 16 + ln][quad * 8];
        o[rt][t] = mfma16(af0, vf0, o[rt][t]);
        bf16x8 vf1 = *(const bf16x8*)&Vs[buf][1][t * 16 + ln][quad * 8];
        o[rt][t] = mfma16(af1, vf1, o[rt][t]);
      }
    }
  }

#pragma unroll
  for (int rt = 0; rt < 2; ++rt)
#pragma unroll
    for (int r = 0; r < 4; ++r) {
      float inv_l = 1.0f / l_r[rt][r];
      int srow = qt * 128 + w * 32 + rt * 16 + quad * 4 + r;
      u16* dst = CTX + (size_t)(b * SEQ_ + srow) * (NH_ * HD_) + h * HD_;
#pragma unroll
      for (int t = 0; t < 8; ++t) dst[t * 16 + ln] = f2bf(o[rt][t][r] * inv_l);
    }
}

extern "C" void kernel_launch(void* const* d_in, const int* in_sizes, int n_in,
                              void* d_out, int out_size, void* d_ws,
                              size_t ws_size, hipStream_t stream) {
  const float* x = (const float*)d_in[0];
  const float* wq = (const float*)d_in[1];
  const float* wk = (const float*)d_in[2];
  const float* wv = (const float*)d_in[3];
  const float* wo = (const float*)d_in[4];
  const float* qw = (const float*)d_in[5];
  const float* kw = (const float*)d_in[6];
  float* out = (float*)d_out;
  char* ws = (char*)d_ws;
  const size_t MB = 1024 * 1024;

  //  [0,48M):  WQKVT bf16 [6144][4096]  -> after qkv_gemm: WOT bf16 at [0,32M)
  //  [48,64M): Xb bf16 [2048][4096]     (dead after qkv_gemm)
  //  [64,88M): qkv bf16 [2048][6144]    -> ctx at [64,80M) after attn inputs built
  //  [88,104M): qb  [104,108M): kb  [108,112M): VT [16][128][1024]
  u16* wqkvt = (u16*)ws;
  u16* wot = (u16*)ws;
  u16* xb = (u16*)(ws + 48 * MB);
  u16* qkv = (u16*)(ws + 64 * MB);
  u16* ctx = (u16*)(ws + 64 * MB);
  u16* qb = (u16*)(ws + 88 * MB);
  u16* kb = (u16*)(ws + 104 * MB);
  u16* vt = (u16*)(ws + 108 * MB);

  cvt_bf16<<<dim3(4096), 256, 0, stream>>>(x, xb);
  transpose_cvt3<<<dim3(128, 192), 256, 0, stream>>>(wq, wk, wv, wqkvt);
  gemm_bt<false><<<dim3(48, 16), 256, 0, stream>>>(xb, wqkvt, qkv, 4096, 6144);
  transpose_cvt<<<dim3(128, 128), 256, 0, stream>>>(wo, 4096, wot, 4096);
  norm_rope<<<dim3(20480), 256, 0, stream>>>(qkv, qw, kw, qb, kb);
  v_transpose<<<dim3(32, 4, 16), 256, 0, stream>>>(qkv, vt);
  flash_attn<<<dim3(512), 256, 0, stream>>>(qb, kb, vt, ctx);
  gemm_bt<true><<<dim3(32, 16), 256, 0, stream>>>(ctx, wot, out, 4096, 4096);
}

// Round 5
// 534.755 us; speedup vs baseline: 1.0559x; 1.0559x over previous
//
#include <hip/hip_runtime.h>

// FlashQwenAttention: x@wq/wk/wv -> rmsnorm(q,k) -> rope -> GQA causal attn -> ctx@wo
// B=2 S=1024 H=4096 NH=32 NKV=8 HD=128. Inputs fp32; internal bf16 MFMA.
// R5: revert flash_attn to R3 (64-row Q tiles, single-buffered, 4 blocks/CU —
// cross-block TLP beats explicit dbuf which cost residency); fuse prep
// dispatches into prep_all (pre-gemm) and mid_all (post-gemm). 5 launches.

#define NH_ 32
#define NKV_ 8
#define HD_ 128
#define SEQ_ 1024
#define HID_ 4096
#define NQKV_ 6144

typedef unsigned short u16;
typedef __bf16 bf16x8 __attribute__((ext_vector_type(8)));
typedef float f32x4 __attribute__((ext_vector_type(4)));

__device__ __forceinline__ u16 f2bf(float f) {
  unsigned int u = __float_as_uint(f);
  return (u16)((u + 0x7FFFu + ((u >> 16) & 1u)) >> 16);
}
__device__ __forceinline__ float bf2f(u16 u) {
  return __uint_as_float(((unsigned int)u) << 16);
}
__device__ __forceinline__ f32x4 mfma16(bf16x8 a, bf16x8 b, f32x4 c) {
  return __builtin_amdgcn_mfma_f32_16x16x32_bf16(a, b, c, 0, 0, 0);
}
__device__ __forceinline__ void gld16(u16* lds, const u16* g) {
  __builtin_amdgcn_global_load_lds(
      (const __attribute__((address_space(1))) unsigned int*)g,
      (__attribute__((address_space(3))) unsigned int*)lds, 16, 0, 0);
}

// ---------------- prep_all: x->bf16 cvt + wq/wk/wv transpose ----------------
// blocks [0,4096): cvt_bf16 of X (8 elems/thread)
// blocks [4096, 28672): 32x32 transpose tiles of wq|wk|wv
__global__ __launch_bounds__(256) void prep_all(
    const float* __restrict__ x, const float* __restrict__ wq,
    const float* __restrict__ wk, const float* __restrict__ wv,
    u16* __restrict__ xb, u16* __restrict__ wqkvt) {
  const int blk = blockIdx.x;
  if (blk < 4096) {
    int i = (blk * 256 + threadIdx.x) * 8;
    float4 a = *(const float4*)(x + i);
    float4 b = *(const float4*)(x + i + 4);
    u16 o[8];
    o[0] = f2bf(a.x); o[1] = f2bf(a.y); o[2] = f2bf(a.z); o[3] = f2bf(a.w);
    o[4] = f2bf(b.x); o[5] = f2bf(b.y); o[6] = f2bf(b.z); o[7] = f2bf(b.w);
    *(uint4*)(xb + i) = *(uint4*)&o[0];
    return;
  }
  __shared__ float t[32][33];
  const int tt = blk - 4096;
  const int k0 = (tt & 127) * 32;
  const int y = tt >> 7;
  const float* src;
  int ldn, n0;
  size_t dofs;
  if (y < 128) { src = wq; ldn = 4096; n0 = y * 32; dofs = 0; }
  else if (y < 160) { src = wk; ldn = 1024; n0 = (y - 128) * 32; dofs = (size_t)4096 * 4096; }
  else { src = wv; ldn = 1024; n0 = (y - 160) * 32; dofs = (size_t)5120 * 4096; }
  const int c = threadIdx.x & 31, r4 = threadIdx.x >> 5;
#pragma unroll
  for (int i = 0; i < 4; ++i) {
    int r = r4 + i * 8;
    t[r][c] = src[(size_t)(k0 + r) * ldn + n0 + c];
  }
  __syncthreads();
#pragma unroll
  for (int i = 0; i < 4; ++i) {
    int r = r4 + i * 8;
    wqkvt[dofs + (size_t)(n0 + r) * HID_ + k0 + c] = f2bf(t[c][r]);
  }
}

// ---------------- mid_all: wo transpose + norm_rope + v_transpose ----------
// blocks [0,16384): wo 32x32 transpose tiles
// blocks [16384,36864): norm_rope (4 vecs/block)
// blocks [36864,38912): v_transpose 32x32 tiles
__global__ __launch_bounds__(256) void mid_all(
    const float* __restrict__ wo, const u16* __restrict__ QKV,
    const float* __restrict__ QW, const float* __restrict__ KW,
    u16* __restrict__ wot, u16* __restrict__ QB, u16* __restrict__ KB,
    u16* __restrict__ VT) {
  const int blk = blockIdx.x;
  if (blk < 16384) {  // wo transpose
    __shared__ float t[32][33];
    const int k0 = (blk & 127) * 32, n0 = (blk >> 7) * 32;
    const int c = threadIdx.x & 31, r4 = threadIdx.x >> 5;
#pragma unroll
    for (int i = 0; i < 4; ++i) {
      int r = r4 + i * 8;
      t[r][c] = wo[(size_t)(k0 + r) * HID_ + n0 + c];
    }
    __syncthreads();
#pragma unroll
    for (int i = 0; i < 4; ++i) {
      int r = r4 + i * 8;
      wot[(size_t)(n0 + r) * HID_ + k0 + c] = f2bf(t[c][r]);
    }
    return;
  }
  if (blk < 36864) {  // norm_rope
    const float QSCALE = 0.08838834764831845f * 1.4426950408889634f;
    int vec = (blk - 16384) * 4 + (threadIdx.x >> 6);
    int lane = threadIdx.x & 63;
    const u16* src;
    u16* dst;
    const float* nw;
    int m;
    float outsc;
    if (vec < 65536) {  // q
      m = vec >> 5;
      int hh = vec & 31;
      src = QKV + (size_t)m * NQKV_ + hh * 128;
      int b = m >> 10, s = m & 1023;
      dst = QB + (size_t)((b * NH_ + hh) * SEQ_ + s) * HD_;
      nw = QW;
      outsc = QSCALE;
    } else {  // k
      int vk = vec - 65536;
      m = vk >> 3;
      int kvh = vk & 7;
      src = QKV + (size_t)m * NQKV_ + 4096 + kvh * 128;
      int b = m >> 10, s = m & 1023;
      dst = KB + (size_t)((b * NKV_ + kvh) * SEQ_ + s) * HD_;
      nw = KW;
      outsc = 1.0f;
    }
    float t1 = bf2f(src[lane]), t2 = bf2f(src[lane + 64]);
    float ss = t1 * t1 + t2 * t2;
#pragma unroll
    for (int off = 32; off >= 1; off >>= 1) ss += __shfl_xor(ss, off);
    float scale = rsqrtf(ss * (1.0f / 128.0f) + 1e-6f) * outsc;
    float n1 = t1 * scale * nw[lane];
    float n2 = t2 * scale * nw[lane + 64];
    int spos = m & 1023;
    float invf = powf(10000.0f, -(float)lane * (1.0f / 64.0f));
    float ang = (float)spos * invf;
    float sn, cs;
    sincosf(ang, &sn, &cs);
    dst[lane] = f2bf(n1 * cs - n2 * sn);
    dst[lane + 64] = f2bf(n1 * sn + n2 * cs);
    return;
  }
  {  // v_transpose
    __shared__ u16 t[32][33];
    const int tt = blk - 36864;
    const int s0 = (tt & 31) * 32, d0 = ((tt >> 5) & 3) * 32;
    const int bkvh = tt >> 7;
    const int b = bkvh >> 3, kvh = bkvh & 7;
    const int c = threadIdx.x & 31, r8 = threadIdx.x >> 5;
#pragma unroll
    for (int i = 0; i < 4; ++i) {
      int r = r8 + i * 8;
      t[r][c] =
          QKV[(size_t)(b * SEQ_ + s0 + r) * NQKV_ + 5120 + kvh * 128 + d0 + c];
    }
    __syncthreads();
#pragma unroll
    for (int i = 0; i < 4; ++i) {
      int r = r8 + i * 8;
      VT[(size_t)(bkvh * HD_ + d0 + r) * SEQ_ + s0 + c] = t[c][r];
    }
  }
}

// ---------------- m97-style GEMM: C[M x N] = A[M x K] @ Bt[N x K]^T --------
template <bool F32OUT>
__global__ __launch_bounds__(256) void gemm_bt(const u16* __restrict__ A,
                                               const u16* __restrict__ Bt,
                                               void* __restrict__ Cv, int K,
                                               int ldc) {
  __shared__ u16 As[128 * 32];
  __shared__ u16 Bs[128 * 32];
  const int bn = blockIdx.x, bm = blockIdx.y;
  const int tid = threadIdx.x, lane = tid & 63, w = tid >> 6;
  const int wr = w >> 1, wc = w & 1, ln = lane & 15, quad = lane >> 4;

  const int srow = w * 32 + (lane >> 2);
  const int skk = (lane & 3) * 8;
  const u16* ag = A + (size_t)(bm * 128 + srow) * K + skk;
  const u16* bg = Bt + (size_t)(bn * 128 + srow) * K + skk;
  u16* asd = &As[w * 1024];
  u16* bsd = &Bs[w * 1024];

  f32x4 acc[4][4];
#pragma unroll
  for (int i = 0; i < 4; ++i)
#pragma unroll
    for (int j = 0; j < 4; ++j)
#pragma unroll
      for (int r = 0; r < 4; ++r) acc[i][j][r] = 0.0f;

  for (int kb = 0; kb < K / 32; ++kb) {
    gld16(asd, ag);
    gld16(asd + 512, ag + 16 * (size_t)K);
    gld16(bsd, bg);
    gld16(bsd + 512, bg + 16 * (size_t)K);
    ag += 32;
    bg += 32;
    __syncthreads();
    bf16x8 af[4], bfr[4];
#pragma unroll
    for (int i = 0; i < 4; ++i)
      af[i] = *(const bf16x8*)&As[(wr * 64 + i * 16 + ln) * 32 + quad * 8];
#pragma unroll
    for (int j = 0; j < 4; ++j)
      bfr[j] = *(const bf16x8*)&Bs[(wc * 64 + j * 16 + ln) * 32 + quad * 8];
#pragma unroll
    for (int i = 0; i < 4; ++i)
#pragma unroll
      for (int j = 0; j < 4; ++j) acc[i][j] = mfma16(af[i], bfr[j], acc[i][j]);
    __syncthreads();
  }
#pragma unroll
  for (int i = 0; i < 4; ++i) {
#pragma unroll
    for (int r = 0; r < 4; ++r) {
      int grow = bm * 128 + wr * 64 + i * 16 + quad * 4 + r;
      int gcol = bn * 128 + wc * 64 + ln;
      if (F32OUT) {
        float* dst = (float*)Cv + (size_t)grow * ldc + gcol;
#pragma unroll
        for (int j = 0; j < 4; ++j) dst[j * 16] = acc[i][j][r];
      } else {
        u16* dst = (u16*)Cv + (size_t)grow * ldc + gcol;
#pragma unroll
        for (int j = 0; j < 4; ++j) dst[j * 16] = f2bf(acc[i][j][r]);
      }
    }
  }
}

// ---------------- GQA causal flash attention (R3 version) ----------------
// block = (b, h, 64-row q tile); 4 waves x 16 q rows; qt-descending order
__global__ __launch_bounds__(256) void flash_attn(
    const u16* __restrict__ QB, const u16* __restrict__ KB,
    const u16* __restrict__ VT, u16* __restrict__ CTX) {
  __shared__ u16 Ks[4][64][32];   // [kc][key][k-seg]   16 KB
  __shared__ u16 Vs[2][128][32];  // [kchunk][d][key]   16 KB
  __shared__ u16 Pl[4][16][72];   // per-wave P, A-layout, XOR-bit3 swizzle

  const int bid = blockIdx.x;
  const int qt = 15 - (bid >> 6);  // long blocks dispatch first
  const int h = bid & 31, b = (bid >> 5) & 1;
  const int kvh = h >> 2;
  const int tid = threadIdx.x, w = tid >> 6, lane = tid & 63;
  const int ln = lane & 15, quad = lane >> 4;
  const int l4 = lane >> 2, l4r = lane & 3;

  const u16* qbase =
      QB + (size_t)((b * NH_ + h) * SEQ_ + qt * 64 + w * 16 + ln) * HD_;
  bf16x8 qf[4];
#pragma unroll
  for (int kc = 0; kc < 4; ++kc)
    qf[kc] = *(const bf16x8*)(qbase + kc * 32 + quad * 8);

  f32x4 o[8];
#pragma unroll
  for (int t = 0; t < 8; ++t)
#pragma unroll
    for (int r = 0; r < 4; ++r) o[t][r] = 0.0f;
  float m_r[4] = {-3e38f, -3e38f, -3e38f, -3e38f};
  float l_r[4] = {0.0f, 0.0f, 0.0f, 0.0f};

  const u16* krow =
      KB + (size_t)((b * NKV_ + kvh) * SEQ_ + w * 16 + l4) * HD_ + l4r * 8;
  const u16* vrow =
      VT + (size_t)((b * NKV_ + kvh) * HD_ + w * 32 + l4) * SEQ_ + l4r * 8;
  const int pswz = ((ln >> 3) & 1) << 3;

  for (int kt = 0; kt <= qt; ++kt) {
    const int key0 = kt * 64;
#pragma unroll
    for (int i = 0; i < 4; ++i)
      gld16(&Ks[i][w * 16][0], krow + (size_t)key0 * HD_ + i * 32);
#pragma unroll
    for (int i = 0; i < 4; ++i)
      gld16(&Vs[i & 1][w * 32 + (i >> 1) * 16][0],
            vrow + (size_t)(i >> 1) * 16 * SEQ_ + key0 + (i & 1) * 32);
    __syncthreads();

    f32x4 sc[4];
#pragma unroll
    for (int t2 = 0; t2 < 4; ++t2) {
#pragma unroll
      for (int r = 0; r < 4; ++r) sc[t2][r] = 0.0f;
#pragma unroll
      for (int kc = 0; kc < 4; ++kc) {
        bf16x8 kf = *(const bf16x8*)&Ks[kc][t2 * 16 + ln][quad * 8];
        sc[t2] = mfma16(qf[kc], kf, sc[t2]);
      }
    }

    const bool diag = (kt == qt);
    float p[4][4], alpha[4];
#pragma unroll
    for (int r = 0; r < 4; ++r) {
      float s0 = sc[0][r], s1 = sc[1][r], s2 = sc[2][r], s3 = sc[3][r];
      if (diag) {
        const int qi = qt * 64 + w * 16 + quad * 4 + r;
        if (key0 + ln > qi) s0 = -3e38f;
        if (key0 + 16 + ln > qi) s1 = -3e38f;
        if (key0 + 32 + ln > qi) s2 = -3e38f;
        if (key0 + 48 + ln > qi) s3 = -3e38f;
      }
      float mx = fmaxf(fmaxf(s0, s1), fmaxf(s2, s3));
#pragma unroll
      for (int off = 1; off < 16; off <<= 1) mx = fmaxf(mx, __shfl_xor(mx, off));
      float mnew = fmaxf(m_r[r], mx);
      alpha[r] = exp2f(m_r[r] - mnew);
      p[0][r] = exp2f(s0 - mnew);
      p[1][r] = exp2f(s1 - mnew);
      p[2][r] = exp2f(s2 - mnew);
      p[3][r] = exp2f(s3 - mnew);
      float rs = p[0][r] + p[1][r] + p[2][r] + p[3][r];
#pragma unroll
      for (int off = 1; off < 16; off <<= 1) rs += __shfl_xor(rs, off);
      l_r[r] = l_r[r] * alpha[r] + rs;
      m_r[r] = mnew;
    }
#pragma unroll
    for (int t = 0; t < 8; ++t)
#pragma unroll
      for (int r = 0; r < 4; ++r) o[t][r] *= alpha[r];

#pragma unroll
    for (int r = 0; r < 4; ++r) {
      const int row = quad * 4 + r;
      const int wswz = ((row >> 3) & 1) << 3;
#pragma unroll
      for (int t2 = 0; t2 < 4; ++t2)
        Pl[w][row][(t2 * 16 + ln) ^ wswz] = f2bf(p[t2][r]);
    }
    bf16x8 af0 = *(const bf16x8*)&Pl[w][ln][(quad * 8) ^ pswz];
    bf16x8 af1 = *(const bf16x8*)&Pl[w][ln][32 + ((quad * 8) ^ pswz)];
#pragma unroll
    for (int t = 0; t < 8; ++t) {
      bf16x8 vf0 = *(const bf16x8*)&Vs[0][t * 16 + ln][quad * 8];
      o[t] = mfma16(af0, vf0, o[t]);
      bf16x8 vf1 = *(const bf16x8*)&Vs[1][t * 16 + ln][quad * 8];
      o[t] = mfma16(af1, vf1, o[t]);
    }
    __syncthreads();
  }

#pragma unroll
  for (int r = 0; r < 4; ++r) {
    float inv_l = 1.0f / l_r[r];
    int srow = qt * 64 + w * 16 + quad * 4 + r;
    u16* dst = CTX + (size_t)(b * SEQ_ + srow) * (NH_ * HD_) + h * HD_;
#pragma unroll
    for (int t = 0; t < 8; ++t) dst[t * 16 + ln] = f2bf(o[t][r] * inv_l);
  }
}

extern "C" void kernel_launch(void* const* d_in, const int* in_sizes, int n_in,
                              void* d_out, int out_size, void* d_ws,
                              size_t ws_size, hipStream_t stream) {
  const float* x = (const float*)d_in[0];
  const float* wq = (const float*)d_in[1];
  const float* wk = (const float*)d_in[2];
  const float* wv = (const float*)d_in[3];
  const float* wo = (const float*)d_in[4];
  const float* qw = (const float*)d_in[5];
  const float* kw = (const float*)d_in[6];
  float* out = (float*)d_out;
  char* ws = (char*)d_ws;
  const size_t MB = 1024 * 1024;

  //  [0,48M):  WQKVT bf16 [6144][4096]  -> after qkv_gemm: WOT bf16 at [0,32M)
  //  [48,64M): Xb bf16 [2048][4096]     (dead after qkv_gemm)
  //  [64,88M): qkv bf16 [2048][6144]    -> ctx at [64,80M) after mid_all
  //  [88,104M): qb  [104,108M): kb  [108,112M): VT [16][128][1024]
  u16* wqkvt = (u16*)ws;
  u16* wot = (u16*)ws;
  u16* xb = (u16*)(ws + 48 * MB);
  u16* qkv = (u16*)(ws + 64 * MB);
  u16* ctx = (u16*)(ws + 64 * MB);
  u16* qb = (u16*)(ws + 88 * MB);
  u16* kb = (u16*)(ws + 104 * MB);
  u16* vt = (u16*)(ws + 108 * MB);

  prep_all<<<dim3(28672), 256, 0, stream>>>(x, wq, wk, wv, xb, wqkvt);
  gemm_bt<false><<<dim3(48, 16), 256, 0, stream>>>(xb, wqkvt, qkv, 4096, 6144);
  mid_all<<<dim3(38912), 256, 0, stream>>>(wo, qkv, qw, kw, wot, qb, kb, vt);
  flash_attn<<<dim3(1024), 256, 0, stream>>>(qb, kb, vt, ctx);
  gemm_bt<true><<<dim3(32, 16), 256, 0, stream>>>(ctx, wot, out, 4096, 4096);
}